// Round 1
// baseline (76.251 us; speedup 1.0000x reference)
//
#include <hip/hip_runtime.h>

// Problem constants (from reference setup_inputs)
#define BB 16
#define SS 2048
#define EE 128
#define WW 128
#define VV 7
#define WE (WW * EE) // 16384

// K1: v_part[oh*WE + i] = sum_{o in [oh*64, oh*64+64)} out_w[o] * fc_w[o*WE + i]
// Grid: 256 blocks (oh = bid>>7 in {0,1}, ib = bid&127 -> i-chunk of 128), 256 threads.
// Each thread: 8 float4 loads of fc_w (one i-quad across 8 o-rows), LDS 8-way reduce.
__global__ __launch_bounds__(256) void k1_reduce_w(const float* __restrict__ fc_w,
                                                   const float* __restrict__ out_w,
                                                   float* __restrict__ v_part) {
    __shared__ float red[8][128];
    const int bid = blockIdx.x;
    const int oh = bid >> 7;   // o half: 0..1
    const int ib = bid & 127;  // i chunk
    const int t = threadIdx.x;
    const int og = t >> 5;     // o group within half: 0..7 (8 o's each)
    const int il = t & 31;     // i quad within chunk
    const int i = ib * 128 + il * 4;
    const int o0 = oh * 64 + og * 8;

    float4 acc = make_float4(0.f, 0.f, 0.f, 0.f);
#pragma unroll
    for (int oo = 0; oo < 8; ++oo) {
        const int o = o0 + oo;
        const float w = out_w[o];
        const float4 f = *reinterpret_cast<const float4*>(fc_w + (size_t)o * WE + i);
        acc.x += w * f.x;
        acc.y += w * f.y;
        acc.z += w * f.z;
        acc.w += w * f.w;
    }
    *reinterpret_cast<float4*>(&red[og][il * 4]) = acc;
    __syncthreads();
    if (t < 128) {
        float s = 0.f;
#pragma unroll
        for (int g = 0; g < 8; ++g) s += red[g][t];
        v_part[oh * WE + ib * 128 + t] = s;
    }
}

// K2: one block per batch. Count non-pad -> last; window dot vs v; fold biases.
__global__ __launch_bounds__(256) void k2_final(const int* __restrict__ x,
                                                const float* __restrict__ emb,
                                                const float* __restrict__ fc_b,
                                                const float* __restrict__ out_w,
                                                const float* __restrict__ out_b,
                                                const float* __restrict__ v_part,
                                                float* __restrict__ out) {
    __shared__ float embT[EE * 8]; // [e][tok], tok==7 is a zero row (left-pad)
    __shared__ float wred[4];
    __shared__ int cred[4];
    __shared__ int s_last;

    const int b = blockIdx.x;
    const int t = threadIdx.x;
    const int lane = t & 63;
    const int wid = t >> 6;
    const int* xb = x + b * SS;

    // Stage transposed embedding table into LDS (tok in low bits -> <=7 distinct
    // banks per wave-access later; same-tok lanes broadcast => conflict-free).
    for (int idx = t; idx < EE * 8; idx += 256) {
        const int tok = idx & 7;
        const int e = idx >> 3;
        embT[idx] = (tok < VV) ? emb[tok * EE + e] : 0.f;
    }

    // Count non-pad tokens (PAD == 0)
    int cnt = 0;
#pragma unroll
    for (int r = 0; r < SS / 256; ++r) cnt += (xb[r * 256 + t] != 0) ? 1 : 0;
#pragma unroll
    for (int off = 32; off; off >>= 1) cnt += __shfl_down(cnt, off, 64);
    if (lane == 0) cred[wid] = cnt;
    __syncthreads(); // also covers embT staging
    if (t == 0) s_last = cred[0] + cred[1] + cred[2] + cred[3] - 1;
    __syncthreads();
    const int last = s_last;

    // Window dot: thread (k = t&127, eh = t>>7) handles 64 e's for one k.
    const int k = t & 127;
    const int eh = t >> 7;
    const int j = last - (WW - 1) + k;
    const int tok = (j >= 0) ? xb[j] : VV; // VV -> zero row (left-pad)
    float acc = 0.f;
    const float* vp = v_part + k;
    const float* er = embT + tok;
#pragma unroll 8
    for (int e = eh * 64; e < eh * 64 + 64; ++e) {
        const float v = vp[e * 128] + vp[WE + e * 128];
        acc += er[e * 8] * v;
    }
    // Fold channel bias: sum_o out_w[o]*fc_b[o] (threads 0..127 add one term each)
    if (t < 128) acc += out_w[t] * fc_b[t];

#pragma unroll
    for (int off = 32; off; off >>= 1) acc += __shfl_down(acc, off, 64);
    if (lane == 0) wred[wid] = acc;
    __syncthreads();
    if (t == 0) out[b] = wred[0] + wred[1] + wred[2] + wred[3] + out_b[0];
}

extern "C" void kernel_launch(void* const* d_in, const int* in_sizes, int n_in,
                              void* d_out, int out_size, void* d_ws, size_t ws_size,
                              hipStream_t stream) {
    const int* x = (const int*)d_in[0];
    const float* emb = (const float*)d_in[1];
    const float* fc_w = (const float*)d_in[2];
    const float* fc_b = (const float*)d_in[3];
    const float* out_w = (const float*)d_in[4];
    const float* out_b = (const float*)d_in[5];
    float* v_part = (float*)d_ws; // 2 * 16384 floats = 128 KB scratch
    float* out = (float*)d_out;

    k1_reduce_w<<<256, 256, 0, stream>>>(fc_w, out_w, v_part);
    k2_final<<<BB, 256, 0, stream>>>(x, emb, fc_b, out_w, out_b, v_part, out);
}